// Round 5
// baseline (281.601 us; speedup 1.0000x reference)
//
#include <hip/hip_runtime.h>
#include <math.h>

// Soft-BCE, C=32, B=2^20. Round 5 = round 4 with the DPP direction bug fixed.
// Layout: 8 lanes per row; lane l owns cols (l%8)*4..+3 of row c*8 + l/8.
// Each load instruction is 64 lanes x float4, LANE-CONTIGUOUS (1 KB/instr,
// 16 x 64B segments — the minimum), identical to the D2D copy ubench pattern.
// Reductions: quad_perm DPP for xor1/xor2; the quad-crossing step is ONE
// row_shr:4 DPP (dst lane p <- lane p-4, per GCN DPP semantics: the wave-scan
// idiom uses row_shr to pull from LOWER lanes) delivering the low-quad partial
// to the leader lane (sub==4). Zero DS-pipe ops in the hot loop.
// Math in log2 domain, *ln2 once at the end.

#define LOG2E 1.44269504088896340736f
#define LN2   0.69314718055994530942f

#define DPP_QP_XOR1  0xB1    // quad_perm [1,0,3,2]
#define DPP_QP_XOR2  0x4E    // quad_perm [2,3,0,1]
#define DPP_ROW_SHR4 0x114   // row_shr:4 (dst lane p <- src lane p-4 within 16-row)

__global__ void zero_out_kernel(float* out) { out[0] = 0.0f; }

template <int CTRL>
__device__ __forceinline__ float dppf(float v) {
    return __int_as_float(
        __builtin_amdgcn_mov_dpp(__float_as_int(v), CTRL, 0xF, 0xF, true));
}
template <int CTRL>
__device__ __forceinline__ int dppi(int v) {
    return __builtin_amdgcn_mov_dpp(v, CTRL, 0xF, 0xF, true);
}

__global__ __launch_bounds__(256) void softbce_kernel(
    const float* __restrict__ logits,
    const float* __restrict__ target,
    float* __restrict__ out,
    int B)
{
    const int lane = threadIdx.x & 63;
    const int sub  = lane & 7;            // position within the row's 8-lane group
    const int wid  = (blockIdx.x * 256 + threadIdx.x) >> 6;
    const int nw   = (gridDim.x * 256) >> 6;
    const int nChunks = B >> 3;           // 8 rows per wave-iteration
    const int colBase = sub * 4;

    float acc = 0.0f;

    for (int c = wid; c < nChunks; c += nw) {
        const size_t idx = (size_t)c * 64 + lane;      // lane-contiguous float4
        const float4 T = ((const float4*)target)[idx];
        const float4 X = ((const float4*)logits)[idx];

        float tv[4] = {T.x, T.y, T.z, T.w};
        float xv[4] = {X.x, X.y, X.z, X.w};

        float rs = 0.0f;     // partial of sum t*log2(p) + (1-t)*log2(1-p)
        float bv = -1.0f;    // best target value (t in [0,1))
        int   bc = 99;       // best col
        float bl = 0.0f;     // log2(p) at best
        float z0 = 0.0f;     // log2(1-p) at col 0 (valid on sub==0)

        #pragma unroll
        for (int j = 0; j < 4; ++j) {
            float x  = xv[j], t = tv[j];
            float t1 = -x * LOG2E;
            float lg = __builtin_log2f(1.0f + __builtin_exp2f(t1)); // -log2(p)
            float s1 = t1 - lg;                                      // log2(1-p)
            rs = fmaf(-t, t1, rs + s1);        // += t*(-lg) + (1-t)*s1
            if (j == 0) z0 = s1;
            if (t > bv) { bv = t; bc = colBase + j; bl = -lg; }  // first-max
        }

        // ---- quad reductions (subs {0..3} -> cols 0..15, subs {4..7} -> 16..31)
        rs += dppf<DPP_QP_XOR1>(rs);
        rs += dppf<DPP_QP_XOR2>(rs);
        {
            float ov = dppf<DPP_QP_XOR1>(bv); int oc = dppi<DPP_QP_XOR1>(bc); float ol = dppf<DPP_QP_XOR1>(bl);
            bool tk = (ov > bv) || (ov == bv && oc < bc);
            bv = tk ? ov : bv; bc = tk ? oc : bc; bl = tk ? ol : bl;
        }
        {
            float ov = dppf<DPP_QP_XOR2>(bv); int oc = dppi<DPP_QP_XOR2>(bc); float ol = dppf<DPP_QP_XOR2>(bl);
            bool tk = (ov > bv) || (ov == bv && oc < bc);
            bv = tk ? ov : bv; bc = tk ? oc : bc; bl = tk ? ol : bl;
        }

        // ---- cross-quad hop: leader lane (sub==4; row positions 4 and 12)
        // receives the low quad's partials from positions 0 and 8 (row_shr:4).
        float ors = dppf<DPP_ROW_SHR4>(rs);
        float obv = dppf<DPP_ROW_SHR4>(bv);
        int   obc = dppi<DPP_ROW_SHR4>(bc);
        float obl = dppf<DPP_ROW_SHR4>(bl);
        float oz0 = dppf<DPP_ROW_SHR4>(z0);   // sub==0 lane's z0 -> leader

        // On the leader: o* = cols 0..15 side, plain = cols 16..31 side.
        float rs_tot = rs + ors;
        bool tk = (obv > bv) || (obv == bv && obc < bc);  // obc<16<=bc: tie->low
        float fbv = tk ? obv : bv;
        int   fbc = tk ? obc : bc;
        float fbl = tk ? obl : bl;

        // label==0: mean over classes; else t_lab*log(p_lab) + 1*log(1-p)[0]
        float loss = (fbc == 0) ? rs_tot * (1.0f / 32.0f) : fmaf(fbv, fbl, oz0);
        if (sub == 4) acc += loss;            // exactly one lane per row
    }

    // ---- once-per-wave reduction (DS cost negligible: 6 ops per wave total)
    #pragma unroll
    for (int d = 1; d < 64; d <<= 1) acc += __shfl_xor(acc, d);

    __shared__ float sacc[4];
    if ((threadIdx.x & 63) == 0) sacc[threadIdx.x >> 6] = acc;
    __syncthreads();
    if (threadIdx.x == 0) {
        float s = sacc[0] + sacc[1] + sacc[2] + sacc[3];
        atomicAdd(out, s * (-LN2 / (float)B));   // out = -mean(per_row), log2->ln
    }
}

extern "C" void kernel_launch(void* const* d_in, const int* in_sizes, int n_in,
                              void* d_out, int out_size, void* d_ws, size_t ws_size,
                              hipStream_t stream) {
    const float* logits = (const float*)d_in[0];
    const float* target = (const float*)d_in[1];
    float* out = (float*)d_out;

    const int B = in_sizes[0] / 32;   // C = 32

    zero_out_kernel<<<1, 1, 0, stream>>>(out);
    // 2048 blocks = 8 blocks/CU, 32 waves/CU; 16 chunks per wave
    softbce_kernel<<<2048, 256, 0, stream>>>(logits, target, out, B);
}